// Round 2
// baseline (454.192 us; speedup 1.0000x reference)
//
#include <hip/hip_runtime.h>
#include <hip/hip_bf16.h>

#define NGRAPH 4096
#define MAXN 384   // max nodes per graph; Binomial(5e5, 1/4096) max ~165, 384 is >20 sigma

typedef __attribute__((ext_vector_type(8))) short s16x8;
typedef __attribute__((ext_vector_type(4))) float f32x4;

__device__ inline short f2bf(float f) {
  unsigned u = __float_as_uint(f);
  unsigned r = u + 0x7fffu + ((u >> 16) & 1u);
  return (short)(r >> 16);
}

// Prepack W1 (256x128 fp32, row-major) into bf16 MFMA B-fragment order.
// Fragment f = kt*8 + ct (kt,ct in 0..7). Lane l supplies B[k][c] for
// k = kt*32 + (l>>4)*8 + e (e=0..7), c = ct*16 + (l&15).
__global__ void prepack_w1(const float* __restrict__ W1, s16x8* __restrict__ w1p) {
  int t = blockIdx.x * 256 + threadIdx.x;   // 4096 threads total
  int f = t >> 6, l = t & 63;
  int kt = f >> 3, ct = f & 7;
  int k0 = kt * 32 + ((l >> 4) * 8);
  int c  = ct * 16 + (l & 15);
  s16x8 v;
  #pragma unroll
  for (int e = 0; e < 8; ++e) v[e] = f2bf(W1[(k0 + e) * 128 + c]);
  w1p[f * 64 + l] = v;
}

__device__ inline long long getb(const void* b, int i, int is64) {
  if (is64) return ((const long long*)b)[i];
  return (long long)((const int*)b)[i];
}

__device__ inline int lowb(const void* b, int n, long long v, int is64) {
  int lo = 0, hi = n;
  while (lo < hi) {
    int mid = (lo + hi) >> 1;
    if (getb(b, mid, is64) < v) lo = mid + 1; else hi = mid;
  }
  return lo;
}

// One-time: offs[g] = lower_bound(batch, g), g = 0..NGRAPH. 4097 independent
// binary searches, fully parallel (latency hidden by TLP); batch (2-4 MB) is
// L2/L3-resident after the first touches.
__global__ void seg_offsets(const void* __restrict__ batch, int* __restrict__ offs, int N) {
  int g = blockIdx.x * 256 + threadIdx.x;
  // int64 vs int32 materialization probe: an odd 32-bit word index is a zero
  // high word under int64 (values < 2^31), a near-max sorted id under int32.
  int probe = ((N & 1) == 0) ? (N - 1) : (N - 2);
  const int is64 = (((const int*)batch)[probe] == 0) ? 1 : 0;
  if (g <= NGRAPH) offs[g] = lowb(batch, N, (long long)g, is64);
}

__device__ inline float fast_tanh(float v) {
  v = fminf(fmaxf(v, -15.f), 15.f);
  float e = __expf(2.f * v);
  return __fdividef(e - 1.f, e + 1.f);
}

__global__ __launch_bounds__(256, 4)
void attnpool(const float* __restrict__ x, const int* __restrict__ offs,
              const float* __restrict__ b1, const float* __restrict__ W2,
              const float* __restrict__ b2p, const s16x8* __restrict__ w1p,
              float* __restrict__ pooled, float* __restrict__ wout, int N)
{
  __shared__ float spart[2][MAXN];
  __shared__ float sred[8];

  const int g = blockIdx.x;
  const int tid = threadIdx.x;
  const int w = tid >> 6, l = tid & 63;
  const int colhalf = w & 1;            // waves 0,2 -> cols 0..63; waves 1,3 -> 64..127
  const int l15 = l & 15, lg = l >> 4;

  const int s = offs[g];
  const int e = offs[g + 1];
  const int cnt = min(e - s, MAXN);     // clamp is a never-taken safety net

  // B fragments for this wave's 64 columns x K=256 (32 frags). The compiler
  // may keep these in VGPRs or rematerialize from w1p (L2-resident) per tile.
  s16x8 bf[4][8];
  #pragma unroll
  for (int ctl = 0; ctl < 4; ++ctl) {
    #pragma unroll
    for (int kt = 0; kt < 8; ++kt)
      bf[ctl][kt] = w1p[(kt * 8 + colhalf * 4 + ctl) * 64 + l];
  }

  float b1v[4], w2v[4];
  #pragma unroll
  for (int ctl = 0; ctl < 4; ++ctl) {
    int c = colhalf * 64 + ctl * 16 + l15;
    b1v[ctl] = b1[c];
    w2v[ctl] = W2[c];
  }
  const float b2s = b2p[0];

  // ---- Phase 1: gate scores via MFMA (16-node tiles; wave pair per tile) ----
  const int tiles = (cnt + 15) >> 4;
  for (int t = (w >> 1); t < tiles; t += 2) {
    const int tb = t * 16;
    int row = s + tb + l15;
    if (row >= N) row = N - 1;          // pad rows: garbage, discarded below
    const float* xp = x + (size_t)row * 256 + lg * 8;
    // Issue all 16 loads for the tile before converting (MLP for latency hiding).
    float4 xl[8][2];
    #pragma unroll
    for (int kt = 0; kt < 8; ++kt) {
      xl[kt][0] = *(const float4*)(xp + kt * 32);
      xl[kt][1] = *(const float4*)(xp + kt * 32 + 4);
    }
    f32x4 acc0 = {0.f,0.f,0.f,0.f}, acc1 = {0.f,0.f,0.f,0.f};
    f32x4 acc2 = {0.f,0.f,0.f,0.f}, acc3 = {0.f,0.f,0.f,0.f};
    #pragma unroll
    for (int kt = 0; kt < 8; ++kt) {
      s16x8 a;
      a[0] = f2bf(xl[kt][0].x); a[1] = f2bf(xl[kt][0].y);
      a[2] = f2bf(xl[kt][0].z); a[3] = f2bf(xl[kt][0].w);
      a[4] = f2bf(xl[kt][1].x); a[5] = f2bf(xl[kt][1].y);
      a[6] = f2bf(xl[kt][1].z); a[7] = f2bf(xl[kt][1].w);
      acc0 = __builtin_amdgcn_mfma_f32_16x16x32_bf16(a, bf[0][kt], acc0, 0, 0, 0);
      acc1 = __builtin_amdgcn_mfma_f32_16x16x32_bf16(a, bf[1][kt], acc1, 0, 0, 0);
      acc2 = __builtin_amdgcn_mfma_f32_16x16x32_bf16(a, bf[2][kt], acc2, 0, 0, 0);
      acc3 = __builtin_amdgcn_mfma_f32_16x16x32_bf16(a, bf[3][kt], acc3, 0, 0, 0);
    }
    // Epilogue: h = tanh(acc + b1), partial score = sum h*W2 over this wave's cols.
    // D layout: row = 4*(l>>4)+r (node in tile), col = l&15.
    float part[4];
    #pragma unroll
    for (int r = 0; r < 4; ++r) part[r] = colhalf ? 0.f : b2s;
    #pragma unroll
    for (int r = 0; r < 4; ++r) {
      part[r] += fast_tanh(acc0[r] + b1v[0]) * w2v[0];
      part[r] += fast_tanh(acc1[r] + b1v[1]) * w2v[1];
      part[r] += fast_tanh(acc2[r] + b1v[2]) * w2v[2];
      part[r] += fast_tanh(acc3[r] + b1v[3]) * w2v[3];
    }
    #pragma unroll
    for (int m = 1; m <= 8; m <<= 1) {
      #pragma unroll
      for (int r = 0; r < 4; ++r) part[r] += __shfl_xor(part[r], m, 64);
    }
    if (l15 == 0) {
      #pragma unroll
      for (int r = 0; r < 4; ++r) {
        int nl = tb + lg * 4 + r;
        if (nl < cnt) spart[colhalf][nl] = part[r];
      }
    }
  }
  __syncthreads();

  if (cnt > 0) {
    // ---- Phase 2: segment softmax (deterministic, no atomics) ----
    float lmax = -1e30f;
    for (int i = tid; i < cnt; i += 256) {
      float sc = spart[0][i] + spart[1][i];
      spart[0][i] = sc;
      lmax = fmaxf(lmax, sc);
    }
    #pragma unroll
    for (int m = 1; m <= 32; m <<= 1) lmax = fmaxf(lmax, __shfl_xor(lmax, m, 64));
    if (l == 0) sred[w] = lmax;
    __syncthreads();
    const float gmax = fmaxf(fmaxf(sred[0], sred[1]), fmaxf(sred[2], sred[3]));
    float lsum = 0.f;
    for (int i = tid; i < cnt; i += 256) {
      float ev = __expf(spart[0][i] - gmax);
      spart[0][i] = ev;
      lsum += ev;
    }
    #pragma unroll
    for (int m = 1; m <= 32; m <<= 1) lsum += __shfl_xor(lsum, m, 64);
    if (l == 0) sred[4 + w] = lsum;
    __syncthreads();
    const float inv = 1.f / (sred[4] + sred[5] + sred[6] + sred[7]);
    for (int i = tid; i < cnt; i += 256) {
      float wt = spart[0][i] * inv;
      spart[0][i] = wt;
      wout[s + i] = wt;
    }
    __syncthreads();

    // ---- Phase 3: pooled[g][col] = sum_n w_n * x[s+n][col], col = tid ----
    float pacc = 0.f;
    const float* xg = x + (size_t)s * 256 + tid;
    int n = 0;
    for (; n + 8 <= cnt; n += 8) {
      float wv[8], xv[8];
      #pragma unroll
      for (int u = 0; u < 8; ++u) {
        wv[u] = spart[0][n + u];
        xv[u] = xg[(size_t)(n + u) * 256];
      }
      #pragma unroll
      for (int u = 0; u < 8; ++u) pacc += wv[u] * xv[u];
    }
    for (; n < cnt; ++n) pacc += spart[0][n] * xg[(size_t)n * 256];
    pooled[(size_t)g * 256 + tid] = pacc;
  } else {
    pooled[(size_t)g * 256 + tid] = 0.f;   // empty segment -> zeros (matches ref guard)
  }
}

extern "C" void kernel_launch(void* const* d_in, const int* in_sizes, int n_in,
                              void* d_out, int out_size, void* d_ws, size_t ws_size,
                              hipStream_t stream) {
  const float* x     = (const float*)d_in[0];
  const void*  batch = d_in[1];
  const float* W1    = (const float*)d_in[2];
  const float* b1    = (const float*)d_in[3];
  const float* W2    = (const float*)d_in[4];
  const float* b2    = (const float*)d_in[5];
  const int N = in_sizes[0] / 256;

  float* pooled = (float*)d_out;
  float* wout   = (float*)d_out + (size_t)NGRAPH * 256;
  s16x8* w1p    = (s16x8*)d_ws;                       // 64 KB
  int*   offs   = (int*)((char*)d_ws + 64 * 1024);    // 4097 * 4 B

  prepack_w1<<<16, 256, 0, stream>>>(W1, w1p);
  seg_offsets<<<17, 256, 0, stream>>>(batch, offs, N);
  attnpool<<<NGRAPH, 256, 0, stream>>>(x, offs, b1, W2, b2, w1p, pooled, wout, N);
}

// Round 3
// 423.505 us; speedup vs baseline: 1.0725x; 1.0725x over previous
//
#include <hip/hip_runtime.h>
#include <hip/hip_bf16.h>

#define NGRAPH 4096
#define MAXN 384   // max nodes/graph; Binomial(5e5,1/4096) max ~165, 384 is >20 sigma

typedef __attribute__((ext_vector_type(8))) short s16x8;
typedef __attribute__((ext_vector_type(4))) float f32x4;

__device__ inline short f2bf(float f) {
  unsigned u = __float_as_uint(f);
  unsigned r = u + 0x7fffu + ((u >> 16) & 1u);
  return (short)(r >> 16);
}

// Prepack W1 (256x128 fp32, row-major) into bf16 MFMA B-fragment order.
// Fragment f = kt*8 + ct (kt,ct in 0..7). Lane l supplies B[k][c] for
// k = kt*32 + (l>>4)*8 + e (e=0..7), c = ct*16 + (l&15).
__global__ void prepack_w1(const float* __restrict__ W1, s16x8* __restrict__ w1p) {
  int t = blockIdx.x * 256 + threadIdx.x;   // 4096 threads total
  int f = t >> 6, l = t & 63;
  int kt = f >> 3, ct = f & 7;
  int k0 = kt * 32 + ((l >> 4) * 8);
  int c  = ct * 16 + (l & 15);
  s16x8 v;
  #pragma unroll
  for (int e = 0; e < 8; ++e) v[e] = f2bf(W1[(k0 + e) * 128 + c]);
  w1p[f * 64 + l] = v;
}

__device__ inline long long getb(const void* b, int i, int is64) {
  if (is64) return ((const long long*)b)[i];
  return (long long)((const int*)b)[i];
}

__device__ inline int lowb(const void* b, int n, long long v, int is64) {
  int lo = 0, hi = n;
  while (lo < hi) {
    int mid = (lo + hi) >> 1;
    if (getb(b, mid, is64) < v) lo = mid + 1; else hi = mid;
  }
  return lo;
}

// One-time: offs[g] = lower_bound(batch, g). 4097 independent searches,
// latency hidden by TLP; batch (2-4 MB) L2/L3-resident after first touches.
__global__ void seg_offsets(const void* __restrict__ batch, int* __restrict__ offs, int N) {
  int g = blockIdx.x * 256 + threadIdx.x;
  // int64 vs int32 materialization probe: an odd 32-bit word index has a zero
  // high word under int64 (values < 2^31), a near-max sorted id under int32.
  int probe = ((N & 1) == 0) ? (N - 1) : (N - 2);
  const int is64 = (((const int*)batch)[probe] == 0) ? 1 : 0;
  if (g <= NGRAPH) offs[g] = lowb(batch, N, (long long)g, is64);
}

__device__ inline float fast_tanh(float v) {
  v = fminf(fmaxf(v, -15.f), 15.f);
  float e = __expf(2.f * v);
  return __fdividef(e - 1.f, e + 1.f);
}

// One block per graph, 256 threads (4 waves). Per 32-node chunk:
//   waves compute gate scores via MFMA (wave-pair wp owns 16 nodes,
//   colhalf owns 64 of 128 hidden cols), then ALL threads do an online
//   (flash-style) softmax-weighted accumulation pacc[col=tid] += ex*x[n][tid],
//   re-reading x rows that are L1/L2-hot from the score pass.
// No big register arrays: B-fragments are loaded inline from L2-resident w1p.
__global__ __launch_bounds__(256, 4)
void attnpool(const float* __restrict__ x, const int* __restrict__ offs,
              const float* __restrict__ b1, const float* __restrict__ W2,
              const float* __restrict__ b2p, const s16x8* __restrict__ w1p,
              float* __restrict__ pooled, float* __restrict__ wout, int N)
{
  __shared__ float sraw[2][2][32];  // [parity][colhalf][node_local]
  __shared__ float sc[MAXN];        // raw combined scores (for wout pass)

  const int g = blockIdx.x;
  const int tid = threadIdx.x;
  const int w = tid >> 6, l = tid & 63;
  const int colhalf = w & 1;        // waves 0,2 -> cols 0..63; 1,3 -> 64..127
  const int wp = w >> 1;            // wave-pair: which 16-node subchunk
  const int l15 = l & 15, lg = l >> 4;

  const int s = offs[g];
  const int cnt = min(offs[g + 1] - s, MAXN);   // clamp: never-taken safety net

  float b1v[4], w2v[4];
  #pragma unroll
  for (int ct = 0; ct < 4; ++ct) {
    int c = colhalf * 64 + ct * 16 + l15;
    b1v[ct] = b1[c];
    w2v[ct] = W2[c];
  }
  const float b2s = b2p[0];

  float pacc = 0.f;      // per-thread (col=tid) weighted sum, at running max pm
  float psum = 0.f;      // block-uniform (redundantly computed per thread)
  float pm   = -1e30f;   // running max
  int par = 0;

  for (int tb = 0; tb < cnt; tb += 32, par ^= 1) {
    const int nt = min(32, cnt - tb);
    const int base = tb + wp * 16;

    if (base < cnt) {
      int row = s + base + l15;
      if (row >= N) row = N - 1;              // pad rows: discarded below
      const float* xp = x + (size_t)row * 256 + lg * 8;
      f32x4 acc0 = {0.f,0.f,0.f,0.f}, acc1 = {0.f,0.f,0.f,0.f};
      f32x4 acc2 = {0.f,0.f,0.f,0.f}, acc3 = {0.f,0.f,0.f,0.f};
      #pragma unroll
      for (int kt = 0; kt < 8; ++kt) {
        float4 xa = *(const float4*)(xp + kt * 32);
        float4 xb = *(const float4*)(xp + kt * 32 + 4);
        const s16x8* wb = w1p + (kt * 8 + colhalf * 4) * 64 + l;
        s16x8 bf0 = wb[0], bf1 = wb[64], bf2 = wb[128], bf3 = wb[192];
        s16x8 a;
        a[0] = f2bf(xa.x); a[1] = f2bf(xa.y); a[2] = f2bf(xa.z); a[3] = f2bf(xa.w);
        a[4] = f2bf(xb.x); a[5] = f2bf(xb.y); a[6] = f2bf(xb.z); a[7] = f2bf(xb.w);
        acc0 = __builtin_amdgcn_mfma_f32_16x16x32_bf16(a, bf0, acc0, 0, 0, 0);
        acc1 = __builtin_amdgcn_mfma_f32_16x16x32_bf16(a, bf1, acc1, 0, 0, 0);
        acc2 = __builtin_amdgcn_mfma_f32_16x16x32_bf16(a, bf2, acc2, 0, 0, 0);
        acc3 = __builtin_amdgcn_mfma_f32_16x16x32_bf16(a, bf3, acc3, 0, 0, 0);
      }
      // h = tanh(acc + b1); partial score = sum h*W2 over this wave's 64 cols.
      // D layout: node-in-tile = 4*lg + r, hidden-col = ct*16 + l15.
      float part[4];
      #pragma unroll
      for (int r = 0; r < 4; ++r) {
        part[r] = colhalf ? 0.f : b2s;
        part[r] += fast_tanh(acc0[r] + b1v[0]) * w2v[0];
        part[r] += fast_tanh(acc1[r] + b1v[1]) * w2v[1];
        part[r] += fast_tanh(acc2[r] + b1v[2]) * w2v[2];
        part[r] += fast_tanh(acc3[r] + b1v[3]) * w2v[3];
      }
      #pragma unroll
      for (int m = 1; m <= 8; m <<= 1) {
        #pragma unroll
        for (int r = 0; r < 4; ++r) part[r] += __shfl_xor(part[r], m, 64);
      }
      if (l15 == 0) {
        #pragma unroll
        for (int r = 0; r < 4; ++r)
          sraw[par][colhalf][wp * 16 + lg * 4 + r] = part[r];
      }
    }
    __syncthreads();   // single barrier per chunk (parity-buffered sraw)

    // ---- online pooling update (all 256 threads; block-uniform m/psum) ----
    const float* s0 = sraw[par][0];
    const float* s1 = sraw[par][1];
    float tmax = -1e30f;
    for (int i = 0; i < nt; ++i) tmax = fmaxf(tmax, s0[i] + s1[i]);
    const float m = fmaxf(pm, tmax);
    const float scale = __expf(pm - m);     // 0 on first chunk (pm=-1e30)
    pacc *= scale;
    psum *= scale;
    if (tid < nt) sc[tb + tid] = s0[tid] + s1[tid];

    const float* xg = x + (size_t)(s + tb) * 256 + tid;
    int i = 0;
    for (; i + 8 <= nt; i += 8) {
      float xv[8], exv[8];
      #pragma unroll
      for (int u = 0; u < 8; ++u) xv[u] = xg[(size_t)(i + u) * 256];
      #pragma unroll
      for (int u = 0; u < 8; ++u) {
        exv[u] = __expf(s0[i + u] + s1[i + u] - m);
        psum += exv[u];
      }
      #pragma unroll
      for (int u = 0; u < 8; ++u) pacc += exv[u] * xv[u];
    }
    for (; i < nt; ++i) {
      float ex = __expf(s0[i] + s1[i] - m);
      psum += ex;
      pacc += ex * xg[(size_t)i * 256];
    }
    pm = m;
  }

  if (cnt > 0) {
    __syncthreads();   // sc[] written by other threads
    const float inv = 1.f / psum;
    pooled[(size_t)g * 256 + tid] = pacc * inv;
    for (int i = tid; i < cnt; i += 256)
      wout[s + i] = __expf(sc[i] - pm) * inv;
  } else {
    pooled[(size_t)g * 256 + tid] = 0.f;   // empty segment -> zeros (ref guard)
  }
}

extern "C" void kernel_launch(void* const* d_in, const int* in_sizes, int n_in,
                              void* d_out, int out_size, void* d_ws, size_t ws_size,
                              hipStream_t stream) {
  const float* x     = (const float*)d_in[0];
  const void*  batch = d_in[1];
  const float* W1    = (const float*)d_in[2];
  const float* b1    = (const float*)d_in[3];
  const float* W2    = (const float*)d_in[4];
  const float* b2    = (const float*)d_in[5];
  const int N = in_sizes[0] / 256;

  float* pooled = (float*)d_out;
  float* wout   = (float*)d_out + (size_t)NGRAPH * 256;
  s16x8* w1p    = (s16x8*)d_ws;                       // 64 KB
  int*   offs   = (int*)((char*)d_ws + 64 * 1024);    // 4097 * 4 B

  prepack_w1<<<16, 256, 0, stream>>>(W1, w1p);
  seg_offsets<<<17, 256, 0, stream>>>(batch, offs, N);
  attnpool<<<NGRAPH, 256, 0, stream>>>(x, offs, b1, W2, b2, w1p, pooled, wout, N);
}